// Round 5
// baseline (51.865 us; speedup 1.0000x reference)
//
#include <hip/hip_runtime.h>
#include <cstdint>

// MMCL loss: per-row top-K hard negatives.
// M=4096 rows, N=13000 cols fp32; K = int(0.01*(N-1)) = 129.
// loss_row = 5*(1-pos)^2 + mean_{topK negatives}((1+v)^2); output = mean over rows.
//
// One 256-thread block per row. The whole row (13000 = 256 threads x 13
// float4s) is loaded into REGISTERS up front: 13 global_load_dwordx4 issued
// back-to-back per thread (max memory-level parallelism, one waitcnt), then
// all passes run register-resident with fully static indexing.
// Candidates (values > t0=2.0, ~296 expected for N(0,1)) are ballot-compacted
// into per-wave LDS segments (no LDS atomics). The positive column is kept
// during streaming and exactly removed later via uniform scalar corrections.
// An 8-pass 4-bit radix select finds the exact K-th largest negative T;
// loss = sum_{v>T}(1+v)^2 + (K-cnt)*(1+T)^2 (exact under ties, == lax.top_k).
// Pathological distributions fall back to threshold bisection in sortable-key
// space over the register copy (no extra global traffic; never triggered for
// this data, kept for exactness).

constexpr int M_ROWS = 4096;
constexpr int N_COLS = 13000;
constexpr int N4     = N_COLS / 4;        // 3250 float4s (13000 % 4 == 0)
constexpr int KSEL   = 129;               // int(0.01 * 12999)
constexpr int BLOCK  = 256;
constexpr int NWAVE  = BLOCK / 64;        // 4
constexpr int WCAP   = 320;               // per-wave candidate cap (~74 expected)
constexpr int NPT    = 13;                // float4s per thread (12 full + tail)
constexpr int TAIL_BASE = 12 * BLOCK;     // 3072
constexpr int TAIL_N    = N4 - TAIL_BASE; // 178 (< BLOCK)
constexpr float DELTA_C = 5.0f;
constexpr float T0   = 2.0f;
constexpr float SENT = -1e30f;            // sentinel: never exceeds any threshold

// monotone float -> uint32 key (larger float => larger key)
__device__ __forceinline__ uint32_t f2key(float f) {
    uint32_t u = __float_as_uint(f);
    return u ^ ((u & 0x80000000u) ? 0xFFFFFFFFu : 0x80000000u);
}
__device__ __forceinline__ float key2f(uint32_t k) {
    uint32_t u = (k & 0x80000000u) ? (k ^ 0x80000000u) : ~k;
    return __uint_as_float(u);
}

__global__ __launch_bounds__(BLOCK) void row_loss_kernel(
    const float* __restrict__ inputs,
    const int*   __restrict__ targets,
    float*       __restrict__ row_loss)
{
    __shared__ float cand[NWAVE * WCAP];   // per-wave segments
    __shared__ int   s_wcnt[NWAVE];
    __shared__ int   s_hist[16];
    __shared__ float s_fpart[NWAVE];
    __shared__ int   s_ipart[NWAVE];
    __shared__ int   s_bucket;
    __shared__ int   s_need;

    const int row  = blockIdx.x;
    const int tid  = threadIdx.x;
    const int wid  = tid >> 6;
    const int lane = tid & 63;
    const float* rp = inputs + (size_t)row * N_COLS;
    const float4* rp4 = reinterpret_cast<const float4*>(rp);
    const int pos = targets[row];
    const uint64_t below = (1ull << lane) - 1ull;
    float* wseg = cand + wid * WCAP;

    // ---- load entire row into registers: 13 loads in flight per thread ----
    float4 v[NPT];
    #pragma unroll
    for (int k = 0; k < NPT - 1; ++k) v[k] = rp4[tid + k * BLOCK];
    v[NPT - 1] = (tid < TAIL_N) ? rp4[TAIL_BASE + tid]
                                : make_float4(SENT, SENT, SENT, SENT);
    const float pos_v = rp[pos];           // uniform broadcast load

    // one full pass over the register copy; returns wave-uniform match count
    auto stream_pass = [&](float t) -> int {
        int wcnt = 0;
        auto proc = [&](float x) {
            const uint64_t m = __ballot(x > t);
            if (m) {                                   // wave-uniform branch
                if (x > t) {
                    const int slot = wcnt + (int)__popcll(m & below);
                    if (slot < WCAP) wseg[slot] = x;
                }
                wcnt += (int)__popcll(m);              // uniform (scalar) add
            }
        };
        #pragma unroll
        for (int k = 0; k < NPT; ++k) {
            proc(v[k].x); proc(v[k].y); proc(v[k].z); proc(v[k].w);
        }
        return wcnt;
    };

    // ---- candidate collection (common case: one pass at t = 2.0) ----
    uint32_t keyA = 0u;           // bracket: overflow side
    uint32_t keyB = 0xFFFFFFFFu;  // bracket: too-few side
    float t = T0;
    bool collapsed = false;       // K-th largest negative known exactly (Tval)
    float Tval = 0.0f;
    int cnt = 0;                  // this wave's candidate count (uniform)

    for (int iter = 0; iter < 64; ++iter) {
        cnt = stream_pass(t);
        if (lane == 0) s_wcnt[wid] = cnt;
        __syncthreads();
        const int c0 = s_wcnt[0], c1 = s_wcnt[1], c2 = s_wcnt[2], c3 = s_wcnt[3];
        __syncthreads();
        const int total = c0 + c1 + c2 + c3;
        const bool ovf = (c0 > WCAP) | (c1 > WCAP) | (c2 > WCAP) | (c3 > WCAP);
        const int npos = (pos_v > t) ? 1 : 0;   // positive inside candidates?

        if (collapsed || (!ovf && (total - npos) >= KSEL)) break;

        const uint32_t kt = f2key(t);
        if (ovf) keyA = kt; else keyB = kt;
        if (keyB - keyA <= 1u) {
            // no representable float strictly between brackets -> exact T
            Tval = key2f(keyB);
            t = Tval;
            collapsed = true;
            continue;
        }
        t = key2f(keyA + (keyB - keyA) / 2u);
    }

    const int mycnt = cnt < WCAP ? cnt : WCAP;     // wave-uniform
    const uint32_t key_pos = f2key(pos_v);
    const bool pos_in = (pos_v > t);   // positive present in candidate multiset

    // ---- exact K-th largest negative via 8-pass 4-bit radix select ----
    float T;
    if (collapsed) {
        T = Tval;   // candidates are exactly {v > T}, negative count < K
    } else {
        uint32_t hi = 0;   // chosen high bits (low bits zero)
        int need = KSEL;
        for (int shift = 28; shift >= 0; shift -= 4) {
            if (tid < 16) s_hist[tid] = 0;
            __syncthreads();
            const uint32_t maskHigh = (uint32_t)(0xFFFFFFFFull << (shift + 4));
            for (int c = lane; c < mycnt; c += 64) {   // wave scans own segment
                const uint32_t k = f2key(wseg[c]);
                if ((k & maskHigh) == hi)
                    atomicAdd(&s_hist[(k >> shift) & 15], 1);
            }
            __syncthreads();
            if (tid == 0) {
                // remove the positive column's contribution at this level
                if (pos_in && ((key_pos & maskHigh) == hi))
                    s_hist[(key_pos >> shift) & 15] -= 1;
                int cum = 0, b = 15;
                for (; b > 0; --b) {
                    const int h = s_hist[b];
                    if (cum + h >= need) break;
                    cum += h;
                }
                s_bucket = b;
                s_need = need - cum;
            }
            __syncthreads();
            hi |= ((uint32_t)s_bucket) << shift;
            need = s_need;
        }
        T = key2f(hi);
    }

    // ---- sum f(v)=(1+v)^2 over v > T, pad with (K-cnt) copies of f(T) ----
    float s = 0.0f;
    int g = 0;
    for (int c = lane; c < mycnt; c += 64) {
        const float x = wseg[c];
        if (x > T) { const float u = 1.0f + x; s += u * u; ++g; }
    }
    #pragma unroll
    for (int off = 32; off > 0; off >>= 1) {
        s += __shfl_down(s, off);
        g += __shfl_down(g, off);
    }
    if (lane == 0) { s_fpart[wid] = s; s_ipart[wid] = g; }
    __syncthreads();
    if (tid == 0) {
        float ss = s_fpart[0] + s_fpart[1] + s_fpart[2] + s_fpart[3];
        int   gg = s_ipart[0] + s_ipart[1] + s_ipart[2] + s_ipart[3];
        if (pos_in && pos_v > T) {     // exact removal of the positive column
            const float u = 1.0f + pos_v;
            ss -= u * u;
            gg -= 1;
        }
        const float uT = 1.0f + T;
        const float neg = (ss + (float)(KSEL - gg) * uT * uT) / (float)KSEL;
        const float d = 1.0f - pos_v;
        row_loss[row] = DELTA_C * d * d + neg;
    }
}

__global__ __launch_bounds__(1024) void reduce_kernel(
    const float* __restrict__ row_loss, float* __restrict__ out)
{
    __shared__ float s[1024];
    float acc = 0.0f;
    for (int i = threadIdx.x; i < M_ROWS; i += 1024) acc += row_loss[i];
    s[threadIdx.x] = acc;
    __syncthreads();
    for (int off = 512; off > 0; off >>= 1) {
        if (threadIdx.x < off) s[threadIdx.x] += s[threadIdx.x + off];
        __syncthreads();
    }
    if (threadIdx.x == 0) out[0] = s[0] / (float)M_ROWS;
}

extern "C" void kernel_launch(void* const* d_in, const int* in_sizes, int n_in,
                              void* d_out, int out_size, void* d_ws, size_t ws_size,
                              hipStream_t stream) {
    const float* inputs  = (const float*)d_in[0];
    // d_in[1] = targets_ (unused by reference), d_in[3] = GT_MC (unused)
    const int*   targets = (const int*)d_in[2];
    float* row_loss = (float*)d_ws;   // 4096 floats = 16 KB scratch

    row_loss_kernel<<<M_ROWS, BLOCK, 0, stream>>>(inputs, targets, row_loss);
    reduce_kernel<<<1, 1024, 0, stream>>>(row_loss, (float*)d_out);
}